// Round 1
// baseline (3429.764 us; speedup 1.0000x reference)
//
#include <hip/hip_runtime.h>
#include <cstddef>
#include <cstdint>

#define SQ    1023
#define HIDC  2048
#define NQC   10240
#define NKVC  1024

// ======================= RoPE tables =======================
__global__ void k_tables(float* __restrict__ cosT, float* __restrict__ sinT) {
  int idx = blockIdx.x * blockDim.x + threadIdx.x;
  if (idx >= SQ * 64) return;
  int t = idx >> 6, i = idx & 63;
  float inv = powf(10000.0f, -(float)i * (1.0f / 64.0f));
  float f = (float)t * inv;
  cosT[idx] = cosf(f);
  sinT[idx] = sinf(f);
}

// ======================= RoPE apply (in place) =======================
// q_proj flat viewed as (5*1023, 16, 128); position t = row % 1023.
__global__ void k_rope_q(float* __restrict__ q, const float* __restrict__ cosT,
                         const float* __restrict__ sinT) {
  int idx = blockIdx.x * blockDim.x + threadIdx.x;
  if (idx >= 5115 * 16 * 64) return;
  int d  = idx & 63;
  int h  = (idx >> 6) & 15;
  int st = idx >> 10;            // g*1023 + t
  int t  = st % 1023;
  size_t base = (((size_t)st * 16) + h) * 128 + d;
  float x0 = q[base], x1 = q[base + 64];
  float c = cosT[t * 64 + d], s = sinT[t * 64 + d];
  q[base]      = x0 * c - x1 * s;
  q[base + 64] = x1 * c + x0 * s;
}

// kv rows are [K(4*128) | V(4*128)]; rope only on K half.
__global__ void k_rope_k(float* __restrict__ kv, const float* __restrict__ cosT,
                         const float* __restrict__ sinT) {
  int idx = blockIdx.x * blockDim.x + threadIdx.x;
  if (idx >= SQ * 4 * 64) return;
  int d   = idx & 63;
  int kvh = (idx >> 6) & 3;
  int t   = idx >> 8;
  size_t base = (size_t)t * 1024 + kvh * 128 + d;
  float x0 = kv[base], x1 = kv[base + 64];
  float c = cosT[t * 64 + d], s = sinT[t * 64 + d];
  kv[base]      = x0 * c - x1 * s;
  kv[base + 64] = x1 * c + x0 * s;
}

// ======================= f32 SGEMM, 128x128x16 tile, 8x8 micro =======================
// A is row-major with row stride 2048 (true for all three GEMMs here).
// Columns k < ksplit come from A0, k >= ksplit from A1 at column (k - ksplit)
// (fuses the concat([prev_hidden, hidden[:-1]]) A matrix of GEMM2).
#define BM 128
#define BN 128
#define BK 16

__global__ __launch_bounds__(256)
void k_sgemm(const float* __restrict__ A0, const float* __restrict__ A1,
             int ksplit, const float* __restrict__ B, float* __restrict__ C,
             int M, int N, int Kd)
{
  __shared__ float As[BK][BM + 4];
  __shared__ float Bs[BK][BN + 4];
  const int tid = threadIdx.x;
  const int tx = tid & 15, ty = tid >> 4;
  const int row0 = blockIdx.y * BM, col0 = blockIdx.x * BN;
  float acc[8][8];
  #pragma unroll
  for (int i = 0; i < 8; ++i)
    #pragma unroll
    for (int j = 0; j < 8; ++j) acc[i][j] = 0.f;

  for (int k0 = 0; k0 < Kd; k0 += BK) {
    // A tile: 128 rows x 16 cols (float4 per thread x2)
    #pragma unroll
    for (int p = 0; p < 2; ++p) {
      int idx = p * 256 + tid;
      int r = idx >> 2;
      int c = (idx & 3) * 4;
      int gr = row0 + r;
      int gc = k0 + c;
      float4 v = make_float4(0.f, 0.f, 0.f, 0.f);
      if (gr < M) {
        const float* src = (gc < ksplit)
            ? (A0 + (size_t)gr * 2048 + gc)
            : (A1 + (size_t)gr * 2048 + (gc - ksplit));
        v = *reinterpret_cast<const float4*>(src);
      }
      As[c + 0][r] = v.x; As[c + 1][r] = v.y;
      As[c + 2][r] = v.z; As[c + 3][r] = v.w;
    }
    // B tile: 16 rows x 128 cols
    #pragma unroll
    for (int p = 0; p < 2; ++p) {
      int idx = p * 256 + tid;
      int r = idx >> 5;
      int c = (idx & 31) * 4;
      float4 v = *reinterpret_cast<const float4*>(B + (size_t)(k0 + r) * N + col0 + c);
      *reinterpret_cast<float4*>(&Bs[r][c]) = v;
    }
    __syncthreads();
    #pragma unroll
    for (int kk = 0; kk < BK; ++kk) {
      float a[8], b[8];
      #pragma unroll
      for (int i = 0; i < 8; ++i) a[i] = As[kk][ty * 8 + i];
      #pragma unroll
      for (int j = 0; j < 8; ++j) b[j] = Bs[kk][tx * 8 + j];
      #pragma unroll
      for (int i = 0; i < 8; ++i)
        #pragma unroll
        for (int j = 0; j < 8; ++j)
          acc[i][j] = fmaf(a[i], b[j], acc[i][j]);
    }
    __syncthreads();
  }
  #pragma unroll
  for (int i = 0; i < 8; ++i) {
    int gr = row0 + ty * 8 + i;
    if (gr >= M) continue;
    float* dst = C + (size_t)gr * N + col0 + tx * 8;
    *reinterpret_cast<float4*>(dst)     = make_float4(acc[i][0], acc[i][1], acc[i][2], acc[i][3]);
    *reinterpret_cast<float4*>(dst + 4) = make_float4(acc[i][4], acc[i][5], acc[i][6], acc[i][7]);
  }
}

// ======================= Flash attention, f32, QT=32 =======================
// grid.x = g*16+h (80), grid.y = q tile (32). K/V shared across g; kvh = h/4.
#define QT 32

__global__ __launch_bounds__(256)
void k_attn(const float* __restrict__ qr, const float* __restrict__ kvb,
            float* __restrict__ Oatt)
{
  __shared__ float Qs[QT][128];
  __shared__ float Ks[QT][132];   // pad 132: granule (j + d4) % 8 -> even spread
  __shared__ float Vs[QT][128];
  __shared__ float Ss[QT][36];
  __shared__ float mS[QT], lS[QT];

  const int tid = threadIdx.x;
  const int gh = blockIdx.x;
  const int qt = blockIdx.y;
  const int g = gh >> 4, h = gh & 15, kvh = (gh & 15) >> 2;
  const int t0 = qt * QT;
  const float scale = 0.08838834764831845f;  // 1/sqrt(128)

  // load Q tile (32 x 128)
  #pragma unroll
  for (int p = 0; p < 4; ++p) {
    int idx = p * 256 + tid;
    int r = idx >> 5;
    int c = (idx & 31) * 4;
    int t = t0 + r;
    float4 v = make_float4(0.f, 0.f, 0.f, 0.f);
    if (t < SQ)
      v = *reinterpret_cast<const float4*>(qr + (((size_t)(g * SQ + t)) * 16 + h) * 128 + c);
    *reinterpret_cast<float4*>(&Qs[r][c]) = v;
  }
  if (tid < QT) { mS[tid] = -1e30f; lS[tid] = 0.f; }

  float acc[16];
  #pragma unroll
  for (int i = 0; i < 16; ++i) acc[i] = 0.f;

  const int prow = tid >> 3;         // softmax/PV row (0..31), 8 lanes per row
  const int pd   = (tid & 7) * 16;   // PV dim base
  const int sc   = (tid & 7) * 4;    // softmax col base
  const int sj   = tid & 31;         // S column
  const int sib  = (tid >> 5) * 4;   // S row base (4 rows per thread)

  for (int jt = 0; jt <= qt; ++jt) {
    int u0 = jt * QT;
    // stage K/V tile
    #pragma unroll
    for (int p = 0; p < 4; ++p) {
      int idx = p * 256 + tid;
      int r = idx >> 5;
      int c = (idx & 31) * 4;
      int u = u0 + r;
      float4 kq = make_float4(0.f, 0.f, 0.f, 0.f);
      float4 vq = make_float4(0.f, 0.f, 0.f, 0.f);
      if (u < SQ) {
        const float* base = kvb + (size_t)u * 1024 + kvh * 128;
        kq = *reinterpret_cast<const float4*>(base + c);
        vq = *reinterpret_cast<const float4*>(base + 512 + c);
      }
      *reinterpret_cast<float4*>(&Ks[r][c]) = kq;
      *reinterpret_cast<float4*>(&Vs[r][c]) = vq;
    }
    __syncthreads();
    // S = Q K^T * scale (+ causal mask)
    #pragma unroll
    for (int ii = 0; ii < 4; ++ii) {
      int i = sib + ii;
      float dot = 0.f;
      #pragma unroll
      for (int c = 0; c < 128; c += 4) {
        float4 qv  = *reinterpret_cast<const float4*>(&Qs[i][c]);
        float4 kv4 = *reinterpret_cast<const float4*>(&Ks[sj][c]);
        dot = fmaf(qv.x, kv4.x, dot);
        dot = fmaf(qv.y, kv4.y, dot);
        dot = fmaf(qv.z, kv4.z, dot);
        dot = fmaf(qv.w, kv4.w, dot);
      }
      int t = t0 + i, u = u0 + sj;
      Ss[i][sj] = (u <= t && u < SQ) ? dot * scale : -1e30f;
    }
    __syncthreads();
    // online softmax: 8 lanes cooperate per row
    {
      float4 sv = *reinterpret_cast<const float4*>(&Ss[prow][sc]);
      float tmax = fmaxf(fmaxf(sv.x, sv.y), fmaxf(sv.z, sv.w));
      tmax = fmaxf(tmax, __shfl_xor(tmax, 1));
      tmax = fmaxf(tmax, __shfl_xor(tmax, 2));
      tmax = fmaxf(tmax, __shfl_xor(tmax, 4));
      float mold = mS[prow];
      float mnew = fmaxf(mold, tmax);
      float corr = __expf(mold - mnew);
      float p0 = __expf(sv.x - mnew);
      float p1 = __expf(sv.y - mnew);
      float p2 = __expf(sv.z - mnew);
      float p3 = __expf(sv.w - mnew);
      *reinterpret_cast<float4*>(&Ss[prow][sc]) = make_float4(p0, p1, p2, p3);
      float sum = p0 + p1 + p2 + p3;
      sum += __shfl_xor(sum, 1);
      sum += __shfl_xor(sum, 2);
      sum += __shfl_xor(sum, 4);
      if ((tid & 7) == 0) {
        mS[prow] = mnew;
        lS[prow] = lS[prow] * corr + sum;
      }
      #pragma unroll
      for (int i = 0; i < 16; ++i) acc[i] *= corr;
    }
    __syncthreads();
    // PV accumulate
    #pragma unroll 1
    for (int jj = 0; jj < QT; ++jj) {
      float pw = Ss[prow][jj];
      #pragma unroll
      for (int dd = 0; dd < 16; ++dd)
        acc[dd] = fmaf(pw, Vs[jj][pd + dd], acc[dd]);
    }
    __syncthreads();
  }
  int t = t0 + prow;
  if (t < SQ) {
    float inv = 1.f / lS[prow];
    float* dst = Oatt + ((size_t)(g * SQ + t)) * 2048 + h * 128 + pd;
    #pragma unroll
    for (int dd = 0; dd < 16; dd += 4)
      *reinterpret_cast<float4*>(dst + dd) =
          make_float4(acc[dd] * inv, acc[dd + 1] * inv, acc[dd + 2] * inv, acc[dd + 3] * inv);
  }
}

// ======================= launch =======================
extern "C" void kernel_launch(void* const* d_in, const int* in_sizes, int n_in,
                              void* d_out, int out_size, void* d_ws, size_t ws_size,
                              hipStream_t stream) {
  const float* hidden = (const float*)d_in[0];   // (1024, 2048)
  const float* prevh  = (const float*)d_in[1];   // (1023, 2048)
  // d_in[2] attention_mask: exactly causal -1e9 -> handled analytically
  // d_in[3] position_ids: arange(1023) -> handled analytically
  const float* Wq     = (const float*)d_in[4];   // (2048, 10240)
  const float* Wkv    = (const float*)d_in[5];   // (4096, 1024)
  const float* Wo     = (const float*)d_in[6];   // (2048, 2048)
  float* out = (float*)d_out;                    // (5115, 2048)

  float* ws   = (float*)d_ws;
  float* qp   = ws;                    // 1023*10240 = 10,475,520 f32
  float* oatt = qp + 10475520;         // 5115*2048  = 10,475,520 f32
  float* kvb  = oatt + 10475520;       // 1023*1024  =  1,047,552 f32
  float* cosT = kvb + 1047552;         // 1023*64
  float* sinT = cosT + 65472;          // 1023*64

  k_tables<<<dim3((SQ * 64 + 255) / 256), dim3(256), 0, stream>>>(cosT, sinT);

  // q_proj = hidden[1:] @ Wq   (A row stride 2048; hidden+2048 = row 1)
  k_sgemm<<<dim3(NQC / 128, (SQ + 127) / 128), dim3(256), 0, stream>>>(
      hidden + 2048, hidden, 1 << 30, Wq, qp, SQ, NQC, 2048);

  // kv = concat(prev_hidden, hidden[:-1]) @ Wkv
  k_sgemm<<<dim3(NKVC / 128, (SQ + 127) / 128), dim3(256), 0, stream>>>(
      prevh, hidden, 2048, Wkv, kvb, SQ, NKVC, 4096);

  k_rope_q<<<dim3((5115 * 16 * 64 + 255) / 256), dim3(256), 0, stream>>>(qp, cosT, sinT);
  k_rope_k<<<dim3((SQ * 4 * 64 + 255) / 256), dim3(256), 0, stream>>>(kvb, cosT, sinT);

  k_attn<<<dim3(80, 32), dim3(256), 0, stream>>>(qp, kvb, oatt);

  // out = O_att @ Wo
  k_sgemm<<<dim3(2048 / 128, (5115 + 127) / 128), dim3(256), 0, stream>>>(
      oatt, oatt, 1 << 30, Wo, out, 5115, 2048, 2048);
}

// Round 2
// 1816.345 us; speedup vs baseline: 1.8883x; 1.8883x over previous
//
#include <hip/hip_runtime.h>
#include <cstddef>
#include <cstdint>

#define SQ    1023
#define HIDC  2048
#define NQC   10240
#define NKVC  1024

typedef unsigned short ushort_t;
typedef __bf16 bf16x8 __attribute__((ext_vector_type(8)));
typedef float  f32x4  __attribute__((ext_vector_type(4)));

__device__ __forceinline__ ushort_t f2bf(float x) {
  union { float f; uint32_t u; } v; v.f = x;
  uint32_t r = v.u + 0x7fffu + ((v.u >> 16) & 1u);   // RNE
  return (ushort_t)(r >> 16);
}

// ======================= RoPE tables =======================
__global__ void k_tables(float* __restrict__ cosT, float* __restrict__ sinT) {
  int idx = blockIdx.x * blockDim.x + threadIdx.x;
  if (idx >= SQ * 64) return;
  int t = idx >> 6, i = idx & 63;
  float inv = powf(10000.0f, -(float)i * (1.0f / 64.0f));
  float f = (float)t * inv;
  cosT[idx] = cosf(f);
  sinT[idx] = sinf(f);
}

// ======================= RoPE apply (in place) =======================
__global__ void k_rope_q(float* __restrict__ q, const float* __restrict__ cosT,
                         const float* __restrict__ sinT) {
  int idx = blockIdx.x * blockDim.x + threadIdx.x;
  if (idx >= 5115 * 16 * 64) return;
  int d  = idx & 63;
  int h  = (idx >> 6) & 15;
  int st = idx >> 10;            // g*1023 + t
  int t  = st % 1023;
  size_t base = (((size_t)st * 16) + h) * 128 + d;
  float x0 = q[base], x1 = q[base + 64];
  float c = cosT[t * 64 + d], s = sinT[t * 64 + d];
  q[base]      = x0 * c - x1 * s;
  q[base + 64] = x1 * c + x0 * s;
}

__global__ void k_rope_k(float* __restrict__ kv, const float* __restrict__ cosT,
                         const float* __restrict__ sinT) {
  int idx = blockIdx.x * blockDim.x + threadIdx.x;
  if (idx >= SQ * 4 * 64) return;
  int d   = idx & 63;
  int kvh = (idx >> 6) & 3;
  int t   = idx >> 8;
  size_t base = (size_t)t * 1024 + kvh * 128 + d;
  float x0 = kv[base], x1 = kv[base + 64];
  float c = cosT[t * 64 + d], s = sinT[t * 64 + d];
  kv[base]      = x0 * c - x1 * s;
  kv[base + 64] = x1 * c + x0 * s;
}

// ======================= f32 -> bf16 converts =======================
// out[i] = bf16(in[i]), n multiple of 4
__global__ void k_f2b(const float* __restrict__ in, ushort_t* __restrict__ out, int n) {
  int i = (blockIdx.x * blockDim.x + threadIdx.x) * 4;
  if (i >= n) return;
  float4 v = *reinterpret_cast<const float4*>(in + i);
  ushort_t o0 = f2bf(v.x), o1 = f2bf(v.y), o2 = f2bf(v.z), o3 = f2bf(v.w);
  uint2 pk;
  pk.x = (uint32_t)o0 | ((uint32_t)o1 << 16);
  pk.y = (uint32_t)o2 | ((uint32_t)o3 << 16);
  *reinterpret_cast<uint2*>(out + i) = pk;
}

// akv[r][c] = bf16( c<2048 ? prevh[r][c] : hidden[r][c-2048] ), 1023 rows x 4096
__global__ void k_concat_b(const float* __restrict__ prevh, const float* __restrict__ hidden,
                           ushort_t* __restrict__ out) {
  int i = (blockIdx.x * blockDim.x + threadIdx.x) * 4;
  if (i >= SQ * 4096) return;
  int r = i >> 12, c = i & 4095;
  const float* src = (c < 2048) ? (prevh + (size_t)r * 2048 + c)
                                : (hidden + (size_t)r * 2048 + (c - 2048));
  float4 v = *reinterpret_cast<const float4*>(src);
  uint2 pk;
  pk.x = (uint32_t)f2bf(v.x) | ((uint32_t)f2bf(v.y) << 16);
  pk.y = (uint32_t)f2bf(v.z) | ((uint32_t)f2bf(v.w) << 16);
  *reinterpret_cast<uint2*>(out + (size_t)r * 4096 + c) = pk;
}

// ======================= transpose + convert: W [K][N] f32 -> Wt [N][K] bf16 ======
// grid (N/32, K/32), block 256. K, N multiples of 32.
__global__ __launch_bounds__(256)
void k_tconv(const float* __restrict__ in, ushort_t* __restrict__ out, int K, int N) {
  __shared__ float t[32][33];
  int n0 = blockIdx.x * 32, k0 = blockIdx.y * 32;
  int r = threadIdx.x >> 5, c = threadIdx.x & 31;
  #pragma unroll
  for (int p = 0; p < 4; ++p)
    t[p * 8 + r][c] = in[(size_t)(k0 + p * 8 + r) * N + n0 + c];
  __syncthreads();
  #pragma unroll
  for (int p = 0; p < 4; ++p)
    out[(size_t)(n0 + p * 8 + r) * K + k0 + c] = f2bf(t[c][p * 8 + r]);
}

// ======================= bf16 MFMA GEMM (m97 structure) =======================
// C[M][N] f32 = A[M][Kd] bf16 (row stride Kd) @ Bt[N][Kd] bf16 (B transposed).
// 128x128 tile, BK=32, 256 threads = 4 waves (2x2), each wave 64x64 = 4x4 frags.
// A buffer must have ceil(M/128)*128 readable rows (pad rows' garbage unused).
__global__ __launch_bounds__(256)
void k_mfma_gemm(const ushort_t* __restrict__ A, const ushort_t* __restrict__ Bt,
                 float* __restrict__ C, int M, int N, int Kd)
{
  __shared__ __align__(16) ushort_t As[128 * 32];
  __shared__ __align__(16) ushort_t Bs[128 * 32];

  const int tid  = threadIdx.x;
  const int lane = tid & 63;
  const int w    = tid >> 6;
  const int wm   = w >> 1, wn = w & 1;
  const int fr   = lane & 15;            // frag row (A) / col (B)
  const int kg   = (lane >> 4) * 8;      // frag k base
  const int m0   = blockIdx.y * 128, n0 = blockIdx.x * 128;

  const int lrow = lane >> 2;            // staging: row within chunk
  const int lk   = (lane & 3) * 8;       // staging: k elements

  f32x4 acc[4][4];
  #pragma unroll
  for (int i = 0; i < 4; ++i)
    #pragma unroll
    for (int j = 0; j < 4; ++j) acc[i][j] = (f32x4){0.f, 0.f, 0.f, 0.f};

  for (int k0 = 0; k0 < Kd; k0 += 32) {
    #pragma unroll
    for (int c = 0; c < 2; ++c) {
      int ch  = w + c * 4;               // chunk 0..7 -> rows [ch*16, ch*16+16)
      int row = ch * 16 + lrow;
      const ushort_t* ga = A  + (size_t)(m0 + row) * Kd + k0 + lk;
      const ushort_t* gb = Bt + (size_t)(n0 + row) * Kd + k0 + lk;
      __builtin_amdgcn_global_load_lds(
          (const __attribute__((address_space(1))) void*)ga,
          (__attribute__((address_space(3))) void*)(As + ch * 512), 16, 0, 0);
      __builtin_amdgcn_global_load_lds(
          (const __attribute__((address_space(1))) void*)gb,
          (__attribute__((address_space(3))) void*)(Bs + ch * 512), 16, 0, 0);
    }
    __syncthreads();

    bf16x8 av[4], bv[4];
    #pragma unroll
    for (int mi = 0; mi < 4; ++mi)
      av[mi] = *reinterpret_cast<const bf16x8*>(As + (wm * 64 + mi * 16 + fr) * 32 + kg);
    #pragma unroll
    for (int nj = 0; nj < 4; ++nj)
      bv[nj] = *reinterpret_cast<const bf16x8*>(Bs + (wn * 64 + nj * 16 + fr) * 32 + kg);
    #pragma unroll
    for (int mi = 0; mi < 4; ++mi)
      #pragma unroll
      for (int nj = 0; nj < 4; ++nj)
        acc[mi][nj] = __builtin_amdgcn_mfma_f32_16x16x32_bf16(av[mi], bv[nj], acc[mi][nj], 0, 0, 0);
    __syncthreads();
  }

  // C/D layout: col = lane&15, row = (lane>>4)*4 + r
  #pragma unroll
  for (int mi = 0; mi < 4; ++mi) {
    #pragma unroll
    for (int nj = 0; nj < 4; ++nj) {
      int rbase = m0 + wm * 64 + mi * 16 + (lane >> 4) * 4;
      int col   = n0 + wn * 64 + nj * 16 + (lane & 15);
      #pragma unroll
      for (int r = 0; r < 4; ++r) {
        int gr = rbase + r;
        if (gr < M) C[(size_t)gr * N + col] = acc[mi][nj][r];
      }
    }
  }
}

// ======================= Flash attention, f32, QT=32 =======================
#define QT 32

__global__ __launch_bounds__(256)
void k_attn(const float* __restrict__ qr, const float* __restrict__ kvb,
            float* __restrict__ Oatt)
{
  __shared__ float Qs[QT][128];
  __shared__ float Ks[QT][132];
  __shared__ float Vs[QT][128];
  __shared__ float Ss[QT][36];
  __shared__ float mS[QT], lS[QT];

  const int tid = threadIdx.x;
  const int gh = blockIdx.x;
  const int qt = blockIdx.y;
  const int g = gh >> 4, h = gh & 15, kvh = (gh & 15) >> 2;
  const int t0 = qt * QT;
  const float scale = 0.08838834764831845f;  // 1/sqrt(128)

  #pragma unroll
  for (int p = 0; p < 4; ++p) {
    int idx = p * 256 + tid;
    int r = idx >> 5;
    int c = (idx & 31) * 4;
    int t = t0 + r;
    float4 v = make_float4(0.f, 0.f, 0.f, 0.f);
    if (t < SQ)
      v = *reinterpret_cast<const float4*>(qr + (((size_t)(g * SQ + t)) * 16 + h) * 128 + c);
    *reinterpret_cast<float4*>(&Qs[r][c]) = v;
  }
  if (tid < QT) { mS[tid] = -1e30f; lS[tid] = 0.f; }

  float acc[16];
  #pragma unroll
  for (int i = 0; i < 16; ++i) acc[i] = 0.f;

  const int prow = tid >> 3;         // row (0..31), 8 lanes per row
  const int l8   = tid & 7;
  const int sc   = l8 * 4;           // softmax col base
  const int sj   = tid & 31;         // S column
  const int sib  = (tid >> 5) * 4;   // S row base

  for (int jt = 0; jt <= qt; ++jt) {
    int u0 = jt * QT;
    #pragma unroll
    for (int p = 0; p < 4; ++p) {
      int idx = p * 256 + tid;
      int r = idx >> 5;
      int c = (idx & 31) * 4;
      int u = u0 + r;
      float4 kq = make_float4(0.f, 0.f, 0.f, 0.f);
      float4 vq = make_float4(0.f, 0.f, 0.f, 0.f);
      if (u < SQ) {
        const float* base = kvb + (size_t)u * 1024 + kvh * 128;
        kq = *reinterpret_cast<const float4*>(base + c);
        vq = *reinterpret_cast<const float4*>(base + 512 + c);
      }
      *reinterpret_cast<float4*>(&Ks[r][c]) = kq;
      *reinterpret_cast<float4*>(&Vs[r][c]) = vq;
    }
    __syncthreads();
    #pragma unroll
    for (int ii = 0; ii < 4; ++ii) {
      int i = sib + ii;
      float dot = 0.f;
      #pragma unroll
      for (int c = 0; c < 128; c += 4) {
        float4 qv  = *reinterpret_cast<const float4*>(&Qs[i][c]);
        float4 kv4 = *reinterpret_cast<const float4*>(&Ks[sj][c]);
        dot = fmaf(qv.x, kv4.x, dot);
        dot = fmaf(qv.y, kv4.y, dot);
        dot = fmaf(qv.z, kv4.z, dot);
        dot = fmaf(qv.w, kv4.w, dot);
      }
      int t = t0 + i, u = u0 + sj;
      Ss[i][sj] = (u <= t && u < SQ) ? dot * scale : -1e30f;
    }
    __syncthreads();
    {
      float4 sv = *reinterpret_cast<const float4*>(&Ss[prow][sc]);
      float tmax = fmaxf(fmaxf(sv.x, sv.y), fmaxf(sv.z, sv.w));
      tmax = fmaxf(tmax, __shfl_xor(tmax, 1));
      tmax = fmaxf(tmax, __shfl_xor(tmax, 2));
      tmax = fmaxf(tmax, __shfl_xor(tmax, 4));
      float mold = mS[prow];
      float mnew = fmaxf(mold, tmax);
      float corr = __expf(mold - mnew);
      float p0 = __expf(sv.x - mnew);
      float p1 = __expf(sv.y - mnew);
      float p2 = __expf(sv.z - mnew);
      float p3 = __expf(sv.w - mnew);
      *reinterpret_cast<float4*>(&Ss[prow][sc]) = make_float4(p0, p1, p2, p3);
      float sum = p0 + p1 + p2 + p3;
      sum += __shfl_xor(sum, 1);
      sum += __shfl_xor(sum, 2);
      sum += __shfl_xor(sum, 4);
      if (l8 == 0) {
        mS[prow] = mnew;
        lS[prow] = lS[prow] * corr + sum;
      }
      #pragma unroll
      for (int i = 0; i < 16; ++i) acc[i] *= corr;
    }
    __syncthreads();
    // PV accumulate: lane owns dims {l8*4 + 32k + j} -> all 32 banks covered
    #pragma unroll 1
    for (int jj = 0; jj < QT; ++jj) {
      float pw = Ss[prow][jj];
      #pragma unroll
      for (int kq = 0; kq < 4; ++kq) {
        float4 v = *reinterpret_cast<const float4*>(&Vs[jj][l8 * 4 + 32 * kq]);
        acc[kq * 4 + 0] = fmaf(pw, v.x, acc[kq * 4 + 0]);
        acc[kq * 4 + 1] = fmaf(pw, v.y, acc[kq * 4 + 1]);
        acc[kq * 4 + 2] = fmaf(pw, v.z, acc[kq * 4 + 2]);
        acc[kq * 4 + 3] = fmaf(pw, v.w, acc[kq * 4 + 3]);
      }
    }
    __syncthreads();
  }
  int t = t0 + prow;
  if (t < SQ) {
    float inv = 1.f / lS[prow];
    float* dst = Oatt + ((size_t)(g * SQ + t)) * 2048 + h * 128;
    #pragma unroll
    for (int kq = 0; kq < 4; ++kq)
      *reinterpret_cast<float4*>(dst + l8 * 4 + 32 * kq) =
          make_float4(acc[kq * 4 + 0] * inv, acc[kq * 4 + 1] * inv,
                      acc[kq * 4 + 2] * inv, acc[kq * 4 + 3] * inv);
  }
}

// ======================= launch =======================
extern "C" void kernel_launch(void* const* d_in, const int* in_sizes, int n_in,
                              void* d_out, int out_size, void* d_ws, size_t ws_size,
                              hipStream_t stream) {
  const float* hidden = (const float*)d_in[0];   // (1024, 2048)
  const float* prevh  = (const float*)d_in[1];   // (1023, 2048)
  const float* Wq     = (const float*)d_in[4];   // (2048, 10240)
  const float* Wkv    = (const float*)d_in[5];   // (4096, 1024)
  const float* Wo     = (const float*)d_in[6];   // (2048, 2048)
  float* out = (float*)d_out;                    // (5115, 2048)

  float* ws   = (float*)d_ws;
  float* qp    = ws;                              // 10,475,520 f32
  float* kvb   = qp + 10475520;                   //  1,047,552 f32
  float* cosT  = kvb + 1047552;                   //     65,472 f32
  float* sinT  = cosT + 65472;                    //     65,472 f32
  ushort_t* hbf   = (ushort_t*)(sinT + 65472);    // 1024*2048
  ushort_t* akv   = hbf + 2097152;                // 1024*4096
  ushort_t* oattb = akv + 4194304;                // 5120*2048
  ushort_t* wqt   = oattb + 10485760;             // 10240*2048
  ushort_t* wkvt  = wqt + 20971520;               // 1024*4096
  ushort_t* wot   = wkvt + 4194304;               // 2048*2048

  k_tables<<<dim3((SQ * 64 + 255) / 256), dim3(256), 0, stream>>>(cosT, sinT);

  // weight transpose+convert
  k_tconv<<<dim3(NQC / 32, HIDC / 32), dim3(256), 0, stream>>>(Wq, wqt, HIDC, NQC);
  k_tconv<<<dim3(NKVC / 32, 4096 / 32), dim3(256), 0, stream>>>(Wkv, wkvt, 4096, NKVC);
  k_tconv<<<dim3(HIDC / 32, HIDC / 32), dim3(256), 0, stream>>>(Wo, wot, HIDC, HIDC);

  // A-matrix converts
  k_f2b<<<dim3((SQ * 2048 / 4 + 255) / 256), dim3(256), 0, stream>>>(hidden + 2048, hbf, SQ * 2048);
  k_concat_b<<<dim3((SQ * 4096 / 4 + 255) / 256), dim3(256), 0, stream>>>(prevh, hidden, akv);

  // q_proj = hidden[1:] @ Wq
  k_mfma_gemm<<<dim3(NQC / 128, 8), dim3(256), 0, stream>>>(hbf, wqt, qp, SQ, NQC, 2048);
  // kv = concat(prev_hidden, hidden[:-1]) @ Wkv
  k_mfma_gemm<<<dim3(NKVC / 128, 8), dim3(256), 0, stream>>>(akv, wkvt, kvb, SQ, NKVC, 4096);

  k_rope_q<<<dim3((5115 * 16 * 64 + 255) / 256), dim3(256), 0, stream>>>(qp, cosT, sinT);
  k_rope_k<<<dim3((SQ * 4 * 64 + 255) / 256), dim3(256), 0, stream>>>(kvb, cosT, sinT);

  // attention writes O_att into d_out (scratch; fully overwritten by GEMM3)
  k_attn<<<dim3(80, 32), dim3(256), 0, stream>>>(qp, kvb, out);

  // O_att -> bf16
  k_f2b<<<dim3((5115 * 2048 / 4 + 255) / 256), dim3(256), 0, stream>>>(out, oattb, 5115 * 2048);

  // out = O_att @ Wo
  k_mfma_gemm<<<dim3(HIDC / 128, 40), dim3(256), 0, stream>>>(oattb, wot, out, 5115, HIDC, 2048);
}

// Round 3
// 363.798 us; speedup vs baseline: 9.4277x; 4.9927x over previous
//
#include <hip/hip_runtime.h>
#include <cstddef>
#include <cstdint>

#define SQ    1023
#define HIDC  2048
#define NQC   10240
#define NKVC  1024

typedef unsigned short ushort_t;
typedef __bf16 bf16x8 __attribute__((ext_vector_type(8)));
typedef float  f32x4  __attribute__((ext_vector_type(4)));

__device__ __forceinline__ ushort_t f2bf(float x) {
  union { float f; uint32_t u; } v; v.f = x;
  uint32_t r = v.u + 0x7fffu + ((v.u >> 16) & 1u);   // RNE
  return (ushort_t)(r >> 16);
}

// ======================= RoPE tables =======================
__global__ void k_tables(float* __restrict__ cosT, float* __restrict__ sinT) {
  int idx = blockIdx.x * blockDim.x + threadIdx.x;
  if (idx >= SQ * 64) return;
  int t = idx >> 6, i = idx & 63;
  float inv = powf(10000.0f, -(float)i * (1.0f / 64.0f));
  float f = (float)t * inv;
  cosT[idx] = cosf(f);
  sinT[idx] = sinf(f);
}

// ======================= RoPE + scale + bf16 (Q) =======================
// reads f32 q_proj [5115][16][128], writes bf16 qb same layout, * 1/sqrt(128)
__global__ void k_rope_q(const float* __restrict__ q, ushort_t* __restrict__ qb,
                         const float* __restrict__ cosT, const float* __restrict__ sinT) {
  int idx = blockIdx.x * blockDim.x + threadIdx.x;
  if (idx >= 5115 * 16 * 64) return;
  int d  = idx & 63;
  int h  = (idx >> 6) & 15;
  int st = idx >> 10;            // g*1023 + t
  int t  = st % 1023;
  size_t base = (((size_t)st * 16) + h) * 128 + d;
  float x0 = q[base], x1 = q[base + 64];
  float c = cosT[t * 64 + d], s = sinT[t * 64 + d];
  const float sc = 0.08838834764831845f;   // 1/sqrt(128)
  qb[base]      = f2bf((x0 * c - x1 * s) * sc);
  qb[base + 64] = f2bf((x1 * c + x0 * s) * sc);
}

// ======================= RoPE + bf16 (K) =======================
// reads f32 kv [1023][1024] (K half cols 0..511), writes bf16 kb [1024][512]
__global__ void k_rope_k(const float* __restrict__ kv, ushort_t* __restrict__ kb,
                         const float* __restrict__ cosT, const float* __restrict__ sinT) {
  int idx = blockIdx.x * blockDim.x + threadIdx.x;
  if (idx >= SQ * 4 * 64) return;
  int d   = idx & 63;
  int kvh = (idx >> 6) & 3;
  int t   = idx >> 8;
  size_t src = (size_t)t * 1024 + kvh * 128 + d;
  float x0 = kv[src], x1 = kv[src + 64];
  float c = cosT[t * 64 + d], s = sinT[t * 64 + d];
  size_t dst = (size_t)t * 512 + kvh * 128 + d;
  kb[dst]      = f2bf(x0 * c - x1 * s);
  kb[dst + 64] = f2bf(x1 * c + x0 * s);
}

// ======================= V transpose: kv[t][512+v] f32 -> vt[v][t] bf16 =====
// vt is [512][1024] (t padded to 1024, pad col zeroed). grid (16, 32)
__global__ __launch_bounds__(256)
void k_vtrans(const float* __restrict__ kvb, ushort_t* __restrict__ vt) {
  __shared__ float tile[32][33];
  int v0 = blockIdx.x * 32;
  int t0 = blockIdx.y * 32;
  int r = threadIdx.x >> 5, c = threadIdx.x & 31;
  #pragma unroll
  for (int p = 0; p < 4; ++p) {
    int t = t0 + p * 8 + r;
    tile[p * 8 + r][c] = (t < SQ) ? kvb[(size_t)t * 1024 + 512 + v0 + c] : 0.f;
  }
  __syncthreads();
  #pragma unroll
  for (int p = 0; p < 4; ++p) {
    int v = v0 + p * 8 + r;
    vt[(size_t)v * 1024 + t0 + c] = f2bf(tile[c][p * 8 + r]);
  }
}

// ======================= f32 -> bf16 convert =======================
__global__ void k_f2b(const float* __restrict__ in, ushort_t* __restrict__ out, int n) {
  int i = (blockIdx.x * blockDim.x + threadIdx.x) * 4;
  if (i >= n) return;
  float4 v = *reinterpret_cast<const float4*>(in + i);
  uint2 pk;
  pk.x = (uint32_t)f2bf(v.x) | ((uint32_t)f2bf(v.y) << 16);
  pk.y = (uint32_t)f2bf(v.z) | ((uint32_t)f2bf(v.w) << 16);
  *reinterpret_cast<uint2*>(out + i) = pk;
}

// akv[r][c] = bf16( c<2048 ? prevh[r][c] : hidden[r][c-2048] )
__global__ void k_concat_b(const float* __restrict__ prevh, const float* __restrict__ hidden,
                           ushort_t* __restrict__ out) {
  int i = (blockIdx.x * blockDim.x + threadIdx.x) * 4;
  if (i >= SQ * 4096) return;
  int r = i >> 12, c = i & 4095;
  const float* src = (c < 2048) ? (prevh + (size_t)r * 2048 + c)
                                : (hidden + (size_t)r * 2048 + (c - 2048));
  float4 v = *reinterpret_cast<const float4*>(src);
  uint2 pk;
  pk.x = (uint32_t)f2bf(v.x) | ((uint32_t)f2bf(v.y) << 16);
  pk.y = (uint32_t)f2bf(v.z) | ((uint32_t)f2bf(v.w) << 16);
  *reinterpret_cast<uint2*>(out + (size_t)r * 4096 + c) = pk;
}

// ======================= transpose + convert: W [K][N] f32 -> Wt [N][K] bf16 ======
__global__ __launch_bounds__(256)
void k_tconv(const float* __restrict__ in, ushort_t* __restrict__ out, int K, int N) {
  __shared__ float t[32][33];
  int n0 = blockIdx.x * 32, k0 = blockIdx.y * 32;
  int r = threadIdx.x >> 5, c = threadIdx.x & 31;
  #pragma unroll
  for (int p = 0; p < 4; ++p)
    t[p * 8 + r][c] = in[(size_t)(k0 + p * 8 + r) * N + n0 + c];
  __syncthreads();
  #pragma unroll
  for (int p = 0; p < 4; ++p)
    out[(size_t)(n0 + p * 8 + r) * K + k0 + c] = f2bf(t[c][p * 8 + r]);
}

// ======================= bf16 MFMA GEMM (m97 structure) =======================
__global__ __launch_bounds__(256)
void k_mfma_gemm(const ushort_t* __restrict__ A, const ushort_t* __restrict__ Bt,
                 float* __restrict__ C, int M, int N, int Kd)
{
  __shared__ __align__(16) ushort_t As[128 * 32];
  __shared__ __align__(16) ushort_t Bs[128 * 32];

  const int tid  = threadIdx.x;
  const int lane = tid & 63;
  const int w    = tid >> 6;
  const int wm   = w >> 1, wn = w & 1;
  const int fr   = lane & 15;
  const int kg   = (lane >> 4) * 8;
  const int m0   = blockIdx.y * 128, n0 = blockIdx.x * 128;

  const int lrow = lane >> 2;
  const int lk   = (lane & 3) * 8;

  f32x4 acc[4][4];
  #pragma unroll
  for (int i = 0; i < 4; ++i)
    #pragma unroll
    for (int j = 0; j < 4; ++j) acc[i][j] = (f32x4){0.f, 0.f, 0.f, 0.f};

  for (int k0 = 0; k0 < Kd; k0 += 32) {
    #pragma unroll
    for (int c = 0; c < 2; ++c) {
      int ch  = w + c * 4;
      int row = ch * 16 + lrow;
      const ushort_t* ga = A  + (size_t)(m0 + row) * Kd + k0 + lk;
      const ushort_t* gb = Bt + (size_t)(n0 + row) * Kd + k0 + lk;
      __builtin_amdgcn_global_load_lds(
          (const __attribute__((address_space(1))) void*)ga,
          (__attribute__((address_space(3))) void*)(As + ch * 512), 16, 0, 0);
      __builtin_amdgcn_global_load_lds(
          (const __attribute__((address_space(1))) void*)gb,
          (__attribute__((address_space(3))) void*)(Bs + ch * 512), 16, 0, 0);
    }
    __syncthreads();

    bf16x8 av[4], bv[4];
    #pragma unroll
    for (int mi = 0; mi < 4; ++mi)
      av[mi] = *reinterpret_cast<const bf16x8*>(As + (wm * 64 + mi * 16 + fr) * 32 + kg);
    #pragma unroll
    for (int nj = 0; nj < 4; ++nj)
      bv[nj] = *reinterpret_cast<const bf16x8*>(Bs + (wn * 64 + nj * 16 + fr) * 32 + kg);
    #pragma unroll
    for (int mi = 0; mi < 4; ++mi)
      #pragma unroll
      for (int nj = 0; nj < 4; ++nj)
        acc[mi][nj] = __builtin_amdgcn_mfma_f32_16x16x32_bf16(av[mi], bv[nj], acc[mi][nj], 0, 0, 0);
    __syncthreads();
  }

  #pragma unroll
  for (int mi = 0; mi < 4; ++mi) {
    #pragma unroll
    for (int nj = 0; nj < 4; ++nj) {
      int rbase = m0 + wm * 64 + mi * 16 + (lane >> 4) * 4;
      int col   = n0 + wn * 64 + nj * 16 + (lane & 15);
      #pragma unroll
      for (int r = 0; r < 4; ++r) {
        int gr = rbase + r;
        if (gr < M) C[(size_t)gr * N + col] = acc[mi][nj][r];
      }
    }
  }
}

// ======================= MFMA flash attention =======================
// grid (80, 16): x = g*16+h, y -> qt = 15 - y (heavy first). 256 thr = 4 waves.
// Block: 64 q rows (wave w owns rows w*16..+15), KV tiles of 64.
// qb: bf16 [5120][16][128] (pre-scaled, roped). kb: bf16 [1024][4][128] (roped).
// vt: bf16 [4*128][1024] (V transposed). oattb out: bf16 [5120][2048].
__global__ __launch_bounds__(256)
void k_attn_mfma(const ushort_t* __restrict__ qb, const ushort_t* __restrict__ kb,
                 const ushort_t* __restrict__ vt, ushort_t* __restrict__ oattb)
{
  __shared__ __align__(16) ushort_t Ks[64 * 128];   // [kv][128 d], 16-B slot s holds d-slot s^(kv&7)
  __shared__ __align__(16) ushort_t Vs[128 * 64];   // [d][64 kv], 16-B slot s holds kv-slot s^(d&7)
  __shared__ __align__(16) ushort_t Ps[4][16 * 64]; // per-wave P [16 q][64 kv], slot s = (kv>>3)^(q&7)

  const int tid  = threadIdx.x;
  const int lane = tid & 63;
  const int w    = tid >> 6;
  const int l15  = lane & 15;
  const int g4   = lane >> 4;
  const int gh   = blockIdx.x;
  const int g = gh >> 4, h = gh & 15, kvh = (gh & 15) >> 2;
  const int qt = 15 - blockIdx.y;
  const int t0 = qt * 64;

  // Q fragments (A-frag: row=l15, k = kk*32 + g4*8 + j), direct from global
  bf16x8 av[4];
  {
    int t = t0 + w * 16 + l15;
    const ushort_t* qrow = qb + (((size_t)(g * SQ + t)) * 16 + h) * 128;
    #pragma unroll
    for (int kk = 0; kk < 4; ++kk)
      av[kk] = *reinterpret_cast<const bf16x8*>(qrow + kk * 32 + g4 * 8);
  }

  f32x4 acc[8];
  #pragma unroll
  for (int dt = 0; dt < 8; ++dt) acc[dt] = (f32x4){0.f, 0.f, 0.f, 0.f};
  float m[4], l[4];
  #pragma unroll
  for (int r = 0; r < 4; ++r) { m[r] = -1e30f; l[r] = 0.f; }

  ushort_t* pw = &Ps[w][0];

  for (int jt = 0; jt <= qt; ++jt) {
    int u0 = jt * 64;
    // stage K (64x256B) and Vt (128x128B), linear LDS dest + pre-swizzled source
    #pragma unroll
    for (int i = 0; i < 4; ++i) {
      int c = (w * 4 + i) * 64 + lane;
      int kv = c >> 4, sl = c & 15;
      const ushort_t* srck = kb + (size_t)(u0 + kv) * 512 + kvh * 128 + ((sl ^ (kv & 7)) << 3);
      __builtin_amdgcn_global_load_lds(
          (const __attribute__((address_space(1))) void*)srck,
          (__attribute__((address_space(3))) void*)(Ks + (w * 4 + i) * 512), 16, 0, 0);
      int d = c >> 3, sv = c & 7;
      const ushort_t* srcv = vt + (size_t)(kvh * 128 + d) * 1024 + u0 + ((sv ^ (d & 7)) << 3);
      __builtin_amdgcn_global_load_lds(
          (const __attribute__((address_space(1))) void*)srcv,
          (__attribute__((address_space(3))) void*)(Vs + (w * 4 + i) * 512), 16, 0, 0);
    }
    __syncthreads();

    // S = Q K^T  (S[ct]: rows q=g4*4+r (local), cols kv=ct*16+l15)
    f32x4 S[4];
    #pragma unroll
    for (int ct = 0; ct < 4; ++ct) S[ct] = (f32x4){0.f, 0.f, 0.f, 0.f};
    #pragma unroll
    for (int ct = 0; ct < 4; ++ct) {
      int kv = ct * 16 + l15;
      #pragma unroll
      for (int kk = 0; kk < 4; ++kk) {
        bf16x8 bv = *reinterpret_cast<const bf16x8*>(
            Ks + kv * 128 + ((((kk << 2) | g4) ^ (kv & 7)) << 3));
        S[ct] = __builtin_amdgcn_mfma_f32_16x16x32_bf16(av[kk], bv, S[ct], 0, 0, 0);
      }
    }
    // causal mask on diagonal tile
    if (jt == qt) {
      #pragma unroll
      for (int ct = 0; ct < 4; ++ct) {
        int u = u0 + ct * 16 + l15;
        #pragma unroll
        for (int r = 0; r < 4; ++r) {
          int t = t0 + w * 16 + g4 * 4 + r;
          if (u > t) S[ct][r] = -1e30f;
        }
      }
    }
    // online softmax (row owned by 16 lanes: shfl within l15 group)
    float corr[4];
    #pragma unroll
    for (int r = 0; r < 4; ++r) {
      float tm = fmaxf(fmaxf(S[0][r], S[1][r]), fmaxf(S[2][r], S[3][r]));
      tm = fmaxf(tm, __shfl_xor(tm, 1));
      tm = fmaxf(tm, __shfl_xor(tm, 2));
      tm = fmaxf(tm, __shfl_xor(tm, 4));
      tm = fmaxf(tm, __shfl_xor(tm, 8));
      float mn = fmaxf(m[r], tm);
      corr[r] = __expf(m[r] - mn);
      m[r] = mn;
      float ps = 0.f;
      #pragma unroll
      for (int ct = 0; ct < 4; ++ct) {
        float p = __expf(S[ct][r] - mn);
        S[ct][r] = p;
        ps += p;
      }
      ps += __shfl_xor(ps, 1);
      ps += __shfl_xor(ps, 2);
      ps += __shfl_xor(ps, 4);
      ps += __shfl_xor(ps, 8);
      l[r] = l[r] * corr[r] + ps;
    }
    #pragma unroll
    for (int dt = 0; dt < 8; ++dt)
      #pragma unroll
      for (int r = 0; r < 4; ++r) acc[dt][r] *= corr[r];

    // P -> wave-private LDS (bf16, swizzled)
    #pragma unroll
    for (int ct = 0; ct < 4; ++ct) {
      int kv = ct * 16 + l15;
      #pragma unroll
      for (int r = 0; r < 4; ++r) {
        int q = g4 * 4 + r;
        pw[q * 64 + ((((kv >> 3) ^ (q & 7)) << 3) | (kv & 7))] = f2bf(S[ct][r]);
      }
    }
    // O += P V  (A-frag from Ps, B-frag from Vs)
    #pragma unroll
    for (int kk = 0; kk < 2; ++kk) {
      bf16x8 pa = *reinterpret_cast<const bf16x8*>(
          pw + l15 * 64 + ((((kk << 2) | g4) ^ (l15 & 7)) << 3));
      #pragma unroll
      for (int dt = 0; dt < 8; ++dt) {
        int d = dt * 16 + l15;
        bf16x8 vv = *reinterpret_cast<const bf16x8*>(
            Vs + d * 64 + ((((kk << 2) | g4) ^ (d & 7)) << 3));
        acc[dt] = __builtin_amdgcn_mfma_f32_16x16x32_bf16(pa, vv, acc[dt], 0, 0, 0);
      }
    }
    __syncthreads();
  }

  // epilogue: normalize, write bf16
  #pragma unroll
  for (int r = 0; r < 4; ++r) {
    int t = t0 + w * 16 + g4 * 4 + r;
    if (t >= SQ) continue;
    float inv = 1.f / l[r];
    ushort_t* dst = oattb + ((size_t)(g * SQ + t)) * 2048 + h * 128;
    #pragma unroll
    for (int dt = 0; dt < 8; ++dt)
      dst[dt * 16 + l15] = f2bf(acc[dt][r] * inv);
  }
}

// ======================= launch =======================
extern "C" void kernel_launch(void* const* d_in, const int* in_sizes, int n_in,
                              void* d_out, int out_size, void* d_ws, size_t ws_size,
                              hipStream_t stream) {
  const float* hidden = (const float*)d_in[0];   // (1024, 2048)
  const float* prevh  = (const float*)d_in[1];   // (1023, 2048)
  const float* Wq     = (const float*)d_in[4];   // (2048, 10240)
  const float* Wkv    = (const float*)d_in[5];   // (4096, 1024)
  const float* Wo     = (const float*)d_in[6];   // (2048, 2048)
  float* out = (float*)d_out;                    // (5115, 2048) = 10,475,520 f32

  char* ws = (char*)d_ws;
  float*    kvb   = (float*)ws;                        ws += (size_t)1024 * 1024 * 4;
  float*    cosT  = (float*)ws;                        ws += (size_t)65472 * 4;
  float*    sinT  = (float*)ws;                        ws += (size_t)65472 * 4;
  ushort_t* qbb   = (ushort_t*)ws;                     ws += (size_t)5120 * 2048 * 2;
  ushort_t* kb    = (ushort_t*)ws;                     ws += (size_t)1024 * 512 * 2;
  ushort_t* vtb   = (ushort_t*)ws;                     ws += (size_t)512 * 1024 * 2;
  ushort_t* hbf   = (ushort_t*)ws;                     ws += (size_t)1024 * 2048 * 2;
  ushort_t* akv   = (ushort_t*)ws;                     ws += (size_t)1024 * 4096 * 2;
  ushort_t* oattb = (ushort_t*)ws;                     ws += (size_t)5120 * 2048 * 2;
  ushort_t* wqt   = (ushort_t*)ws;                     ws += (size_t)10240 * 2048 * 2;
  ushort_t* wkvt  = (ushort_t*)ws;                     ws += (size_t)1024 * 4096 * 2;
  ushort_t* wot   = (ushort_t*)ws;                     ws += (size_t)2048 * 2048 * 2;

  float* qp = out;   // f32 q_proj scratch lives in d_out (1023*10240 elements, exact fit)

  k_tables<<<dim3((SQ * 64 + 255) / 256), dim3(256), 0, stream>>>(cosT, sinT);

  // weight transpose+convert
  k_tconv<<<dim3(NQC / 32, HIDC / 32), dim3(256), 0, stream>>>(Wq, wqt, HIDC, NQC);
  k_tconv<<<dim3(NKVC / 32, 4096 / 32), dim3(256), 0, stream>>>(Wkv, wkvt, 4096, NKVC);
  k_tconv<<<dim3(HIDC / 32, HIDC / 32), dim3(256), 0, stream>>>(Wo, wot, HIDC, HIDC);

  // A-matrix converts
  k_f2b<<<dim3((SQ * 2048 / 4 + 255) / 256), dim3(256), 0, stream>>>(hidden + 2048, hbf, SQ * 2048);
  k_concat_b<<<dim3((SQ * 4096 / 4 + 255) / 256), dim3(256), 0, stream>>>(prevh, hidden, akv);

  // q_proj = hidden[1:] @ Wq   (f32 C into d_out scratch)
  k_mfma_gemm<<<dim3(NQC / 128, 8), dim3(256), 0, stream>>>(hbf, wqt, qp, SQ, NQC, 2048);
  // kv = concat(prev_hidden, hidden[:-1]) @ Wkv
  k_mfma_gemm<<<dim3(NKVC / 128, 8), dim3(256), 0, stream>>>(akv, wkvt, kvb, SQ, NKVC, 4096);

  // rope + bf16 pack
  k_rope_q<<<dim3((5115 * 16 * 64 + 255) / 256), dim3(256), 0, stream>>>(qp, qbb, cosT, sinT);
  k_rope_k<<<dim3((SQ * 4 * 64 + 255) / 256), dim3(256), 0, stream>>>(kvb, kb, cosT, sinT);
  k_vtrans<<<dim3(16, 32), dim3(256), 0, stream>>>(kvb, vtb);

  // MFMA flash attention -> bf16 O
  k_attn_mfma<<<dim3(80, 16), dim3(256), 0, stream>>>(qbb, kb, vtb, oattb);

  // out = O_att @ Wo
  k_mfma_gemm<<<dim3(HIDC / 128, 40), dim3(256), 0, stream>>>(oattb, wot, out, 5115, HIDC, 2048);
}

// Round 4
// 314.604 us; speedup vs baseline: 10.9018x; 1.1564x over previous
//
#include <hip/hip_runtime.h>
#include <cstddef>
#include <cstdint>

#define SQ    1023
#define HIDC  2048
#define NQC   10240
#define NKVC  1024

typedef unsigned short ushort_t;
typedef __bf16 bf16x8 __attribute__((ext_vector_type(8)));
typedef float  f32x4  __attribute__((ext_vector_type(4)));

__device__ __forceinline__ ushort_t f2bf(float x) {
  union { float f; uint32_t u; } v; v.f = x;
  uint32_t r = v.u + 0x7fffu + ((v.u >> 16) & 1u);   // RNE
  return (ushort_t)(r >> 16);
}

// ======================= RoPE tables =======================
__global__ void k_tables(float* __restrict__ cosT, float* __restrict__ sinT) {
  int idx = blockIdx.x * blockDim.x + threadIdx.x;
  if (idx >= SQ * 64) return;
  int t = idx >> 6, i = idx & 63;
  float inv = powf(10000.0f, -(float)i * (1.0f / 64.0f));
  float f = (float)t * inv;
  cosT[idx] = cosf(f);
  sinT[idx] = sinf(f);
}

// ======================= RoPE + scale + bf16 (Q) =======================
__global__ void k_rope_q(const float* __restrict__ q, ushort_t* __restrict__ qb,
                         const float* __restrict__ cosT, const float* __restrict__ sinT) {
  int idx = blockIdx.x * blockDim.x + threadIdx.x;
  if (idx >= 5115 * 16 * 64) return;
  int d  = idx & 63;
  int h  = (idx >> 6) & 15;
  int st = idx >> 10;            // g*1023 + t
  int t  = st % 1023;
  size_t base = (((size_t)st * 16) + h) * 128 + d;
  float x0 = q[base], x1 = q[base + 64];
  float c = cosT[t * 64 + d], s = sinT[t * 64 + d];
  const float sc = 0.08838834764831845f;   // 1/sqrt(128)
  qb[base]      = f2bf((x0 * c - x1 * s) * sc);
  qb[base + 64] = f2bf((x1 * c + x0 * s) * sc);
}

// ======================= RoPE + bf16 (K), sums 4 split-K partials =======
// kvp: 4 partials of [1023][1024] f32. writes bf16 kb [1024][512]
__global__ void k_rope_k(const float* __restrict__ kvp, ushort_t* __restrict__ kb,
                         const float* __restrict__ cosT, const float* __restrict__ sinT) {
  int idx = blockIdx.x * blockDim.x + threadIdx.x;
  if (idx >= SQ * 4 * 64) return;
  int d   = idx & 63;
  int kvh = (idx >> 6) & 3;
  int t   = idx >> 8;
  size_t src = (size_t)t * 1024 + kvh * 128 + d;
  float x0 = 0.f, x1 = 0.f;
  #pragma unroll
  for (int z = 0; z < 4; ++z) {
    x0 += kvp[(size_t)z * (SQ * 1024) + src];
    x1 += kvp[(size_t)z * (SQ * 1024) + src + 64];
  }
  float c = cosT[t * 64 + d], s = sinT[t * 64 + d];
  size_t dst = (size_t)t * 512 + kvh * 128 + d;
  kb[dst]      = f2bf(x0 * c - x1 * s);
  kb[dst + 64] = f2bf(x1 * c + x0 * s);
}

// ======================= V transpose (sums 4 partials) =======================
// vt is [512][1024] (t padded to 1024, pad col zeroed). grid (16, 32)
__global__ __launch_bounds__(256)
void k_vtrans(const float* __restrict__ kvp, ushort_t* __restrict__ vt) {
  __shared__ float tile[32][33];
  int v0 = blockIdx.x * 32;
  int t0 = blockIdx.y * 32;
  int r = threadIdx.x >> 5, c = threadIdx.x & 31;
  #pragma unroll
  for (int p = 0; p < 4; ++p) {
    int t = t0 + p * 8 + r;
    float s = 0.f;
    if (t < SQ) {
      size_t src = (size_t)t * 1024 + 512 + v0 + c;
      #pragma unroll
      for (int z = 0; z < 4; ++z) s += kvp[(size_t)z * (SQ * 1024) + src];
    }
    tile[p * 8 + r][c] = s;
  }
  __syncthreads();
  #pragma unroll
  for (int p = 0; p < 4; ++p) {
    int v = v0 + p * 8 + r;
    vt[(size_t)v * 1024 + t0 + c] = f2bf(tile[c][p * 8 + r]);
  }
}

// ======================= f32 -> bf16 convert =======================
__global__ void k_f2b(const float* __restrict__ in, ushort_t* __restrict__ out, int n) {
  int i = (blockIdx.x * blockDim.x + threadIdx.x) * 4;
  if (i >= n) return;
  float4 v = *reinterpret_cast<const float4*>(in + i);
  uint2 pk;
  pk.x = (uint32_t)f2bf(v.x) | ((uint32_t)f2bf(v.y) << 16);
  pk.y = (uint32_t)f2bf(v.z) | ((uint32_t)f2bf(v.w) << 16);
  *reinterpret_cast<uint2*>(out + i) = pk;
}

// akv[r][c] = bf16( c<2048 ? prevh[r][c] : hidden[r][c-2048] )
__global__ void k_concat_b(const float* __restrict__ prevh, const float* __restrict__ hidden,
                           ushort_t* __restrict__ out) {
  int i = (blockIdx.x * blockDim.x + threadIdx.x) * 4;
  if (i >= SQ * 4096) return;
  int r = i >> 12, c = i & 4095;
  const float* src = (c < 2048) ? (prevh + (size_t)r * 2048 + c)
                                : (hidden + (size_t)r * 2048 + (c - 2048));
  float4 v = *reinterpret_cast<const float4*>(src);
  uint2 pk;
  pk.x = (uint32_t)f2bf(v.x) | ((uint32_t)f2bf(v.y) << 16);
  pk.y = (uint32_t)f2bf(v.z) | ((uint32_t)f2bf(v.w) << 16);
  *reinterpret_cast<uint2*>(out + (size_t)r * 4096 + c) = pk;
}

// ======================= transpose + convert: W [K][N] f32 -> Wt [N][K] bf16 ======
__global__ __launch_bounds__(256)
void k_tconv(const float* __restrict__ in, ushort_t* __restrict__ out, int K, int N) {
  __shared__ float t[32][33];
  int n0 = blockIdx.x * 32, k0 = blockIdx.y * 32;
  int r = threadIdx.x >> 5, c = threadIdx.x & 31;
  #pragma unroll
  for (int p = 0; p < 4; ++p)
    t[p * 8 + r][c] = in[(size_t)(k0 + p * 8 + r) * N + n0 + c];
  __syncthreads();
  #pragma unroll
  for (int p = 0; p < 4; ++p)
    out[(size_t)(n0 + p * 8 + r) * K + k0 + c] = f2bf(t[c][p * 8 + r]);
}

// ======================= bf16 MFMA GEMM, 64x128 tile =======================
// C[M][N] f32 (+ z*M*N for split-K partials) = A[M][Kd] @ Bt[N][Kd], bf16.
// 4 waves (2x2), each wave 32x64 = 2x4 frags of 16x16x32.
// K-range per block: [blockIdx.z*kLen, +kLen). A needs ceil(M/64)*64 readable rows.
__global__ __launch_bounds__(256)
void k_gemm64(const ushort_t* __restrict__ A, const ushort_t* __restrict__ Bt,
              float* __restrict__ C, int M, int N, int Kd, int kLen)
{
  __shared__ __align__(16) ushort_t As[64 * 32];
  __shared__ __align__(16) ushort_t Bs[128 * 32];

  const int tid  = threadIdx.x;
  const int lane = tid & 63;
  const int w    = tid >> 6;
  const int wm   = w >> 1, wn = w & 1;
  const int fr   = lane & 15;
  const int kg   = (lane >> 4) * 8;
  const int g4   = lane >> 4;
  const int l15  = lane & 15;
  const int m0   = blockIdx.y * 64, n0 = blockIdx.x * 128;
  const int kOff = blockIdx.z * kLen;
  C += (size_t)blockIdx.z * M * N;

  const int arow = tid >> 2, aslot = (tid & 3) * 8;

  f32x4 acc[2][4];
  #pragma unroll
  for (int i = 0; i < 2; ++i)
    #pragma unroll
    for (int j = 0; j < 4; ++j) acc[i][j] = (f32x4){0.f, 0.f, 0.f, 0.f};

  for (int k0 = kOff; k0 < kOff + kLen; k0 += 32) {
    // A tile: 64 rows x 32 k (4 KB), 1 load/thread
    {
      const ushort_t* ga = A + (size_t)(m0 + arow) * Kd + k0 + aslot;
      __builtin_amdgcn_global_load_lds(
          (const __attribute__((address_space(1))) void*)ga,
          (__attribute__((address_space(3))) void*)(As + w * 512), 16, 0, 0);
    }
    // B tile: 128 rows x 32 k (8 KB), 2 loads/thread
    #pragma unroll
    for (int c = 0; c < 2; ++c) {
      int u = c * 256 + tid;
      const ushort_t* gb = Bt + (size_t)(n0 + (u >> 2)) * Kd + k0 + (u & 3) * 8;
      __builtin_amdgcn_global_load_lds(
          (const __attribute__((address_space(1))) void*)gb,
          (__attribute__((address_space(3))) void*)(Bs + (c * 256 + w * 64) * 8), 16, 0, 0);
    }
    __syncthreads();

    bf16x8 av[2], bv[4];
    #pragma unroll
    for (int mi = 0; mi < 2; ++mi)
      av[mi] = *reinterpret_cast<const bf16x8*>(As + (wm * 32 + mi * 16 + fr) * 32 + kg);
    #pragma unroll
    for (int nj = 0; nj < 4; ++nj)
      bv[nj] = *reinterpret_cast<const bf16x8*>(Bs + (wn * 64 + nj * 16 + fr) * 32 + kg);
    #pragma unroll
    for (int mi = 0; mi < 2; ++mi)
      #pragma unroll
      for (int nj = 0; nj < 4; ++nj)
        acc[mi][nj] = __builtin_amdgcn_mfma_f32_16x16x32_bf16(av[mi], bv[nj], acc[mi][nj], 0, 0, 0);
    __syncthreads();
  }

  // C/D layout: col = lane&15, row = (lane>>4)*4 + r
  #pragma unroll
  for (int mi = 0; mi < 2; ++mi) {
    #pragma unroll
    for (int nj = 0; nj < 4; ++nj) {
      int rbase = m0 + wm * 32 + mi * 16 + g4 * 4;
      int col   = n0 + wn * 64 + nj * 16 + l15;
      #pragma unroll
      for (int r = 0; r < 4; ++r) {
        int gr = rbase + r;
        if (gr < M) C[(size_t)gr * N + col] = acc[mi][nj][r];
      }
    }
  }
}

// ======================= MFMA flash attention =======================
// grid (80, 16): x = g*16+h, y -> qt = 15 - y (heavy first). 256 thr = 4 waves.
__global__ __launch_bounds__(256)
void k_attn_mfma(const ushort_t* __restrict__ qb, const ushort_t* __restrict__ kb,
                 const ushort_t* __restrict__ vt, ushort_t* __restrict__ oattb)
{
  __shared__ __align__(16) ushort_t Ks[64 * 128];   // [kv][128 d], 16-B slot s holds d-slot s^(kv&7)
  __shared__ __align__(16) ushort_t Vs[128 * 64];   // [d][64 kv], 16-B slot s holds kv-slot s^(d&7)
  __shared__ __align__(16) ushort_t Ps[4][16 * 64]; // per-wave P [16 q][64 kv], swizzled

  const int tid  = threadIdx.x;
  const int lane = tid & 63;
  const int w    = tid >> 6;
  const int l15  = lane & 15;
  const int g4   = lane >> 4;
  const int gh   = blockIdx.x;
  const int g = gh >> 4, h = gh & 15, kvh = (gh & 15) >> 2;
  const int qt = 15 - blockIdx.y;
  const int t0 = qt * 64;

  bf16x8 av[4];
  {
    int t = t0 + w * 16 + l15;
    const ushort_t* qrow = qb + (((size_t)(g * SQ + t)) * 16 + h) * 128;
    #pragma unroll
    for (int kk = 0; kk < 4; ++kk)
      av[kk] = *reinterpret_cast<const bf16x8*>(qrow + kk * 32 + g4 * 8);
  }

  f32x4 acc[8];
  #pragma unroll
  for (int dt = 0; dt < 8; ++dt) acc[dt] = (f32x4){0.f, 0.f, 0.f, 0.f};
  float m[4], l[4];
  #pragma unroll
  for (int r = 0; r < 4; ++r) { m[r] = -1e30f; l[r] = 0.f; }

  ushort_t* pw = &Ps[w][0];

  for (int jt = 0; jt <= qt; ++jt) {
    int u0 = jt * 64;
    #pragma unroll
    for (int i = 0; i < 4; ++i) {
      int c = (w * 4 + i) * 64 + lane;
      int kv = c >> 4, sl = c & 15;
      const ushort_t* srck = kb + (size_t)(u0 + kv) * 512 + kvh * 128 + ((sl ^ (kv & 7)) << 3);
      __builtin_amdgcn_global_load_lds(
          (const __attribute__((address_space(1))) void*)srck,
          (__attribute__((address_space(3))) void*)(Ks + (w * 4 + i) * 512), 16, 0, 0);
      int d = c >> 3, sv = c & 7;
      const ushort_t* srcv = vt + (size_t)(kvh * 128 + d) * 1024 + u0 + ((sv ^ (d & 7)) << 3);
      __builtin_amdgcn_global_load_lds(
          (const __attribute__((address_space(1))) void*)srcv,
          (__attribute__((address_space(3))) void*)(Vs + (w * 4 + i) * 512), 16, 0, 0);
    }
    __syncthreads();

    f32x4 S[4];
    #pragma unroll
    for (int ct = 0; ct < 4; ++ct) S[ct] = (f32x4){0.f, 0.f, 0.f, 0.f};
    #pragma unroll
    for (int ct = 0; ct < 4; ++ct) {
      int kv = ct * 16 + l15;
      #pragma unroll
      for (int kk = 0; kk < 4; ++kk) {
        bf16x8 bv = *reinterpret_cast<const bf16x8*>(
            Ks + kv * 128 + ((((kk << 2) | g4) ^ (kv & 7)) << 3));
        S[ct] = __builtin_amdgcn_mfma_f32_16x16x32_bf16(av[kk], bv, S[ct], 0, 0, 0);
      }
    }
    if (jt == qt) {
      #pragma unroll
      for (int ct = 0; ct < 4; ++ct) {
        int u = u0 + ct * 16 + l15;
        #pragma unroll
        for (int r = 0; r < 4; ++r) {
          int t = t0 + w * 16 + g4 * 4 + r;
          if (u > t) S[ct][r] = -1e30f;
        }
      }
    }
    float corr[4];
    #pragma unroll
    for (int r = 0; r < 4; ++r) {
      float tm = fmaxf(fmaxf(S[0][r], S[1][r]), fmaxf(S[2][r], S[3][r]));
      tm = fmaxf(tm, __shfl_xor(tm, 1));
      tm = fmaxf(tm, __shfl_xor(tm, 2));
      tm = fmaxf(tm, __shfl_xor(tm, 4));
      tm = fmaxf(tm, __shfl_xor(tm, 8));
      float mn = fmaxf(m[r], tm);
      corr[r] = __expf(m[r] - mn);
      m[r] = mn;
      float ps = 0.f;
      #pragma unroll
      for (int ct = 0; ct < 4; ++ct) {
        float p = __expf(S[ct][r] - mn);
        S[ct][r] = p;
        ps += p;
      }
      ps += __shfl_xor(ps, 1);
      ps += __shfl_xor(ps, 2);
      ps += __shfl_xor(ps, 4);
      ps += __shfl_xor(ps, 8);
      l[r] = l[r] * corr[r] + ps;
    }
    #pragma unroll
    for (int dt = 0; dt < 8; ++dt)
      #pragma unroll
      for (int r = 0; r < 4; ++r) acc[dt][r] *= corr[r];

    #pragma unroll
    for (int ct = 0; ct < 4; ++ct) {
      int kv = ct * 16 + l15;
      #pragma unroll
      for (int r = 0; r < 4; ++r) {
        int q = g4 * 4 + r;
        pw[q * 64 + ((((kv >> 3) ^ (q & 7)) << 3) | (kv & 7))] = f2bf(S[ct][r]);
      }
    }
    #pragma unroll
    for (int kk = 0; kk < 2; ++kk) {
      bf16x8 pa = *reinterpret_cast<const bf16x8*>(
          pw + l15 * 64 + ((((kk << 2) | g4) ^ (l15 & 7)) << 3));
      #pragma unroll
      for (int dt = 0; dt < 8; ++dt) {
        int d = dt * 16 + l15;
        bf16x8 vv = *reinterpret_cast<const bf16x8*>(
            Vs + d * 64 + ((((kk << 2) | g4) ^ (d & 7)) << 3));
        acc[dt] = __builtin_amdgcn_mfma_f32_16x16x32_bf16(pa, vv, acc[dt], 0, 0, 0);
      }
    }
    __syncthreads();
  }

  #pragma unroll
  for (int r = 0; r < 4; ++r) {
    int t = t0 + w * 16 + g4 * 4 + r;
    if (t >= SQ) continue;
    float inv = 1.f / l[r];
    ushort_t* dst = oattb + ((size_t)(g * SQ + t)) * 2048 + h * 128;
    #pragma unroll
    for (int dt = 0; dt < 8; ++dt)
      dst[dt * 16 + l15] = f2bf(acc[dt][r] * inv);
  }
}

// ======================= launch =======================
extern "C" void kernel_launch(void* const* d_in, const int* in_sizes, int n_in,
                              void* d_out, int out_size, void* d_ws, size_t ws_size,
                              hipStream_t stream) {
  const float* hidden = (const float*)d_in[0];   // (1024, 2048)
  const float* prevh  = (const float*)d_in[1];   // (1023, 2048)
  const float* Wq     = (const float*)d_in[4];   // (2048, 10240)
  const float* Wkv    = (const float*)d_in[5];   // (4096, 1024)
  const float* Wo     = (const float*)d_in[6];   // (2048, 2048)
  float* out = (float*)d_out;                    // (5115, 2048)

  char* ws = (char*)d_ws;
  float*    kvp   = (float*)ws;                        ws += (size_t)4 * SQ * 1024 * 4;  // 4 split-K partials
  float*    cosT  = (float*)ws;                        ws += (size_t)65472 * 4;
  float*    sinT  = (float*)ws;                        ws += (size_t)65472 * 4;
  ushort_t* qbb   = (ushort_t*)ws;                     ws += (size_t)5120 * 2048 * 2;
  ushort_t* kb    = (ushort_t*)ws;                     ws += (size_t)1024 * 512 * 2;
  ushort_t* vtb   = (ushort_t*)ws;                     ws += (size_t)512 * 1024 * 2;
  ushort_t* hbf   = (ushort_t*)ws;                     ws += (size_t)1024 * 2048 * 2;
  ushort_t* akv   = (ushort_t*)ws;                     ws += (size_t)1024 * 4096 * 2;
  ushort_t* oattb = (ushort_t*)ws;                     ws += (size_t)5120 * 2048 * 2;
  ushort_t* wqt   = (ushort_t*)ws;                     ws += (size_t)10240 * 2048 * 2;
  ushort_t* wkvt  = (ushort_t*)ws;                     ws += (size_t)1024 * 4096 * 2;
  ushort_t* wot   = (ushort_t*)ws;                     ws += (size_t)2048 * 2048 * 2;

  float* qp = out;   // f32 q_proj scratch lives in d_out (1023*10240 elements, exact fit)

  k_tables<<<dim3((SQ * 64 + 255) / 256), dim3(256), 0, stream>>>(cosT, sinT);

  // weight transpose+convert
  k_tconv<<<dim3(NQC / 32, HIDC / 32), dim3(256), 0, stream>>>(Wq, wqt, HIDC, NQC);
  k_tconv<<<dim3(NKVC / 32, 4096 / 32), dim3(256), 0, stream>>>(Wkv, wkvt, 4096, NKVC);
  k_tconv<<<dim3(HIDC / 32, HIDC / 32), dim3(256), 0, stream>>>(Wo, wot, HIDC, HIDC);

  // A-matrix converts
  k_f2b<<<dim3((SQ * 2048 / 4 + 255) / 256), dim3(256), 0, stream>>>(hidden + 2048, hbf, SQ * 2048);
  k_concat_b<<<dim3((SQ * 4096 / 4 + 255) / 256), dim3(256), 0, stream>>>(prevh, hidden, akv);

  // q_proj = hidden[1:] @ Wq   (1280 blocks, 5/CU)
  k_gemm64<<<dim3(NQC / 128, 16, 1), dim3(256), 0, stream>>>(hbf, wqt, qp, SQ, NQC, 2048, 2048);
  // kv = concat(prev,hidden) @ Wkv, split-K x4 (512 blocks)
  k_gemm64<<<dim3(NKVC / 128, 16, 4), dim3(256), 0, stream>>>(akv, wkvt, kvp, SQ, NKVC, 4096, 1024);

  // rope + bf16 pack (rope_k / vtrans fold the 4 kv partials)
  k_rope_q<<<dim3((5115 * 16 * 64 + 255) / 256), dim3(256), 0, stream>>>(qp, qbb, cosT, sinT);
  k_rope_k<<<dim3((SQ * 4 * 64 + 255) / 256), dim3(256), 0, stream>>>(kvp, kb, cosT, sinT);
  k_vtrans<<<dim3(16, 32), dim3(256), 0, stream>>>(kvp, vtb);

  // MFMA flash attention -> bf16 O
  k_attn_mfma<<<dim3(80, 16), dim3(256), 0, stream>>>(qbb, kb, vtb, oattb);

  // out = O_att @ Wo   (1280 blocks, 5/CU)
  k_gemm64<<<dim3(HIDC / 128, 80, 1), dim3(256), 0, stream>>>(oattb, wot, out, 5115, HIDC, 2048, 2048);
}